// Round 1
// baseline (413.184 us; speedup 1.0000x reference)
//
#include <hip/hip_runtime.h>

#define HID 512
#define ST  256
#define BB  128
#define TT  256
#define BT  (BB*TT)
#define NCH 8
#define CHL 32

typedef unsigned short u16;
typedef unsigned int   u32;
typedef float f32x4  __attribute__((ext_vector_type(4)));
typedef __bf16 bf16x8 __attribute__((ext_vector_type(8)));

// ---- workspace layout (bytes) ----
#define OFF_E    0x0u        // 128 KB  E = expm(A*DT)-I, bf16 [256][256] row-major
#define OFF_W32  0x20000u    // 256 KB  W32 fp32, W32[k*256+s] = Ad32[s][k]
#define OFF_WB   0x60000u    // 256 KB  Wb bf16 [256][512]
#define OFF_WCD  0xA0000u    // 768 KB  Wcd bf16 [512][768]  (k<256: Wc, k>=256: Wd)
#define OFF_BIAS 0x160000u   // 2 KB    bc+bd fp32 [512]
#define OFF_R    0x162000u   // 1 MB    R fp32 [8][128][256]
#define OFF_HC   0x262000u   // 1 MB    Hc fp32 [8][128][256]
#define OFF_U    0x400000u   // 16 MB   u bf16 [BT][256]
#define OFF_HS   0x1400000u  // 16 MB   hs bf16 [BT][256]
#define OFF_XB   0x2400000u  // 32 MB   x bf16 [BT][512]

__device__ __forceinline__ u16 f2bf(float f){
  u32 x = __float_as_uint(f);
  return (u16)((x + 0x7FFFu + ((x>>16)&1u)) >> 16);
}
__device__ __forceinline__ float bf2f(u16 u){
  return __uint_as_float(((u32)u)<<16);
}
__device__ __forceinline__ void gld16(const void* g, void* l){
  __builtin_amdgcn_global_load_lds((const __attribute__((address_space(1))) u32*)g,
                                   (__attribute__((address_space(3))) u32*)l, 16, 0, 0);
}

// =====================================================================
// k_pe: blocks [0,256): strip-Taylor expm (E bf16 and Ad32^T fp32)
//       blocks [256,2304): x->bf16, Wb->bf16, Wcd pack, bias
// =====================================================================
__global__ __launch_bounds__(256) void k_pe(
    const float* __restrict__ x, const float* __restrict__ A,
    const float* __restrict__ Wb, const float* __restrict__ Wc,
    const float* __restrict__ Wd, const float* __restrict__ bc,
    const float* __restrict__ bd, u16* __restrict__ Ebf,
    float* __restrict__ W32, u16* __restrict__ wbb,
    u16* __restrict__ wcdb, float* __restrict__ biascd,
    u16* __restrict__ xb)
{
  __shared__ float cur[2*256];
  int bid = blockIdx.x;
  int tid = threadIdx.x;
  if (bid < 256){
    // ---- matrix exponential via Taylor on 2-row strips ----
    int half = bid >> 7;              // 0: Ad (scale 0.1), 1: Ad^32 (scale 3.2)
    int r0 = (bid & 127)*2;
    float scale = half ? 3.2f : 0.1f;
    int mmax = half ? 14 : 7;
    int r  = tid >> 7;                // 0..1 row within strip
    int c2 = (tid & 127)*2;           // 2 cols per thread
    int row = r0 + r;
    float a0 = A[row*256 + c2]*scale;
    float a1 = A[row*256 + c2 + 1]*scale;
    float s0 = a0, s1 = a1;           // sum of M^m/m!, m>=1 (identity excluded)
    cur[r*256 + c2] = a0; cur[r*256 + c2 + 1] = a1;
    for (int m = 2; m <= mmax; ++m){
      __syncthreads();
      float n0 = 0.f, n1 = 0.f;
      for (int k = 0; k < 256; ++k){
        float ck = cur[r*256 + k];                       // LDS broadcast
        float2 av = ((const float2*)A)[(k*256 + c2)>>1]; // coalesced
        n0 = fmaf(ck, av.x, n0);
        n1 = fmaf(ck, av.y, n1);
      }
      float f = scale/(float)m;
      n0 *= f; n1 *= f;
      s0 += n0; s1 += n1;
      __syncthreads();
      cur[r*256 + c2] = n0; cur[r*256 + c2 + 1] = n1;
    }
    if (!half){
      Ebf[row*256 + c2]     = f2bf(s0);   // E = Ad - I  (no identity added)
      Ebf[row*256 + c2 + 1] = f2bf(s1);
    } else {
      if (c2     == row) s0 += 1.f;
      if (c2 + 1 == row) s1 += 1.f;
      W32[(size_t)c2*256 + row]     = s0; // store transposed: W32[k][s]=Ad32[s][k]
      W32[(size_t)(c2+1)*256 + row] = s1;
    }
    return;
  }
  // ---- prep (grid-stride over 2048 blocks) ----
  long gt = (long)(bid - 256)*256 + tid;
  const long np = 2048l*256l;
  for (long i = gt; i < (long)BT*HID/4; i += np){
    float4 v = ((const float4*)x)[i];
    u32 lo = (u32)f2bf(v.x) | ((u32)f2bf(v.y)<<16);
    u32 hi = (u32)f2bf(v.z) | ((u32)f2bf(v.w)<<16);
    uint2 q; q.x = lo; q.y = hi;
    ((uint2*)xb)[i] = q;
  }
  for (long i = gt; i < (long)ST*HID; i += np) wbb[i] = f2bf(Wb[i]);
  for (long i = gt; i < 512l*768l; i += np){
    int n = (int)(i/768), k = (int)(i%768);
    float v = (k < 256) ? Wc[n*256 + k] : Wd[n*512 + (k-256)];
    wcdb[i] = f2bf(v);
  }
  for (long i = gt; i < 512; i += np) biascd[i] = bc[i] + bd[i];
}

// =====================================================================
// k_bx: u[bt][s] = x_bf16 @ Wb^T + bb   (bf16 MFMA, m97-style)
// grid 512: (bid>>1)=m-tile of 128 rows, (bid&1)=n-tile of 128 cols
// =====================================================================
__global__ __launch_bounds__(256,1) void k_bx(
    const u16* __restrict__ xb, const u16* __restrict__ wb,
    const float* __restrict__ bb, u16* __restrict__ uout)
{
  __shared__ u16 At[2][128*32];
  __shared__ u16 Bt[2][128*32];
  int bid = blockIdx.x;
  int m0 = (bid>>1)*128, n0 = (bid&1)*128;
  int tid = threadIdx.x, lane = tid&63, w = tid>>6, l15 = lane&15, lg = lane>>4;
  int wrow = (w>>1)*64, wcol = (w&1)*64;
  f32x4 acc[4][4] = {};

  auto stage = [&](int buf, int ki){
    #pragma unroll
    for (int p=0;p<2;++p){
      int c = w + p*4;
      int grow = c*16 + (lane>>2);
      int gk = ki*32 + (lane&3)*8;
      gld16(xb + (size_t)(m0+grow)*HID + gk, &At[buf][c*512]);
      gld16(wb + (size_t)(n0+grow)*HID + gk, &Bt[buf][c*512]);
    }
  };
  stage(0,0);
  __syncthreads();
  for (int ki=0; ki<16; ++ki){
    int buf = ki&1;
    if (ki < 15) stage(buf^1, ki+1);
    bf16x8 af[4], bfr[4];
    #pragma unroll
    for (int mi=0;mi<4;++mi)
      af[mi] = *(const bf16x8*)&At[buf][(wrow + mi*16 + l15)*32 + lg*8];
    #pragma unroll
    for (int ni=0;ni<4;++ni)
      bfr[ni] = *(const bf16x8*)&Bt[buf][(wcol + ni*16 + l15)*32 + lg*8];
    #pragma unroll
    for (int mi=0;mi<4;++mi)
      #pragma unroll
      for (int ni=0;ni<4;++ni)
        acc[mi][ni] = __builtin_amdgcn_mfma_f32_16x16x32_bf16(af[mi], bfr[ni], acc[mi][ni], 0,0,0);
    __syncthreads();
  }
  float bb4[4];
  #pragma unroll
  for (int ni=0;ni<4;++ni) bb4[ni] = bb[n0 + wcol + ni*16 + l15];
  #pragma unroll
  for (int mi=0;mi<4;++mi)
    #pragma unroll
    for (int ni=0;ni<4;++ni)
      #pragma unroll
      for (int r=0;r<4;++r){
        int row = m0 + wrow + mi*16 + lg*4 + r;
        int col = n0 + wcol + ni*16 + l15;
        uout[(size_t)row*ST + col] = f2bf(acc[mi][ni][r] + bb4[ni]);
      }
}

// =====================================================================
// k_rec: chunked recurrence  h_t = h_{t-1} + h_{t-1}@E^T (bf16 MFMA) + u_t (fp32)
//   WRITE_HS=false: local pass from 0, writes chunk-final state R[j]
//   WRITE_HS=true : fixup pass from Hc[j], writes hs (bf16) for all t
// grid 64: j = bid>>3 (chunk), b-tile = (bid&7)*16
// =====================================================================
template<bool WRITE_HS>
__global__ __launch_bounds__(256,1) void k_rec(
    const u16* __restrict__ Ebf, const u16* __restrict__ ubuf,
    const float* __restrict__ Hc, float* __restrict__ Rbuf,
    u16* __restrict__ hsb)
{
  int j = blockIdx.x >> 3;
  int b0 = (blockIdx.x & 7)*16;
  int tid = threadIdx.x, lane = tid&63, w = tid>>6, l15 = lane&15, lg = lane>>4;
  __shared__ u16 hlds[2][16*256];

  // preload E fragments (constant across steps): wave w owns s in [w*64, w*64+64)
  bf16x8 ef[4][8];
  #pragma unroll
  for (int nt=0; nt<4; ++nt){
    int srow = w*64 + nt*16 + l15;
    #pragma unroll
    for (int kk=0; kk<8; ++kk)
      ef[nt][kk] = *(const bf16x8*)(Ebf + (size_t)srow*256 + kk*32 + lg*8);
  }

  // acc = h state, fp32, C/D layout: (row = lg*4+r, col = w*64+nt*16+l15)
  f32x4 acc[4];
  #pragma unroll
  for (int nt=0;nt<4;++nt){
    if (WRITE_HS && j > 0){
      #pragma unroll
      for (int r=0;r<4;++r)
        acc[nt][r] = Hc[((size_t)j*BB + b0 + lg*4 + r)*ST + w*64 + nt*16 + l15];
    } else {
      acc[nt] = (f32x4){0.f,0.f,0.f,0.f};
    }
  }

  int t0 = j*CHL;
  for (int it=0; it<CHL; ++it){
    int t = t0 + it;
    // prefetch u_t (independent of LDS traffic below)
    float uv[4][4];
    #pragma unroll
    for (int nt=0;nt<4;++nt)
      #pragma unroll
      for (int r=0;r<4;++r)
        uv[nt][r] = bf2f(ubuf[((size_t)(b0 + lg*4 + r)*TT + t)*ST + w*64 + nt*16 + l15]);
    // stage h_{t-1} (bf16, XOR-swizzled) into double-buffered LDS
    u16* hb = hlds[it&1];
    #pragma unroll
    for (int nt=0;nt<4;++nt)
      #pragma unroll
      for (int r=0;r<4;++r){
        int row = lg*4 + r;
        int sc  = w*64 + nt*16 + l15;
        int off = (row*512 + sc*2) ^ ((row&7)<<4);
        hb[off>>1] = f2bf(acc[nt][r]);
      }
    __syncthreads();
    // A-fragments of h_{t-1}
    bf16x8 af[8];
    #pragma unroll
    for (int kk=0;kk<8;++kk){
      int off = (l15*512 + (kk*32 + lg*8)*2) ^ ((l15&7)<<4);
      af[kk] = *(const bf16x8*)(hb + (off>>1));
    }
    // h += h@E^T
    #pragma unroll
    for (int nt=0;nt<4;++nt)
      #pragma unroll
      for (int kk=0;kk<8;++kk)
        acc[nt] = __builtin_amdgcn_mfma_f32_16x16x32_bf16(af[kk], ef[nt][kk], acc[nt], 0,0,0);
    // h += u_t (fp32 carry)
    #pragma unroll
    for (int nt=0;nt<4;++nt)
      #pragma unroll
      for (int r=0;r<4;++r)
        acc[nt][r] += uv[nt][r];
    if (WRITE_HS){
      #pragma unroll
      for (int nt=0;nt<4;++nt)
        #pragma unroll
        for (int r=0;r<4;++r)
          hsb[((size_t)(b0 + lg*4 + r)*TT + t)*ST + w*64 + nt*16 + l15] = f2bf(acc[nt][r]);
    }
  }
  if (!WRITE_HS){
    #pragma unroll
    for (int nt=0;nt<4;++nt)
      #pragma unroll
      for (int r=0;r<4;++r)
        Rbuf[((size_t)j*BB + b0 + lg*4 + r)*ST + w*64 + nt*16 + l15] = acc[nt][r];
  }
}

// =====================================================================
// k_scan: chunk-carry scan (fp32):  H_1 = R_0;  H_j = Ad32-apply(H_{j-1}) + R_{j-1}
// grid 128 (one block per batch row), thread owns one s
// =====================================================================
__global__ __launch_bounds__(256) void k_scan(
    const float* __restrict__ W32, const float* __restrict__ Rbuf,
    float* __restrict__ Hc)
{
  int b = blockIdx.x;
  int s = threadIdx.x;
  __shared__ float hp[256];
  float h = Rbuf[(size_t)(0*BB + b)*ST + s];
  Hc[(size_t)(1*BB + b)*ST + s] = h;
  for (int j = 2; j < NCH; ++j){
    hp[s] = h;
    __syncthreads();
    float a = Rbuf[(size_t)((j-1)*BB + b)*ST + s];
    #pragma unroll 4
    for (int k=0;k<256;++k)
      a = fmaf(hp[k], W32[(size_t)k*256 + s], a);
    __syncthreads();
    h = a;
    Hc[(size_t)j*BB*ST + (size_t)b*ST + s] = h;
  }
}

// =====================================================================
// k_out: out = LN( hs@Wc^T + x@Wd^T + bc + bd + x ) * gamma + beta
// BM=64, BN=512 (full row => block-local LN), K=768, 8 waves
// =====================================================================
__global__ __launch_bounds__(512,2) void k_out(
    const u16* __restrict__ hsb, const u16* __restrict__ xb,
    const u16* __restrict__ wcd, const float* __restrict__ biascd,
    const float* __restrict__ gamma, const float* __restrict__ beta,
    float* __restrict__ out)
{
  __shared__ u16 At[2][64*32];
  __shared__ u16 Bt[2][512*32];
  __shared__ float redbuf[64][8][2];
  __shared__ float musig[64][2];
  int m0 = blockIdx.x*64;
  int tid = threadIdx.x, lane = tid&63, w = tid>>6, l15 = lane&15, lg = lane>>4;
  f32x4 acc[4][4] = {};

  auto stage = [&](int buf, int ki){
    #pragma unroll
    for (int p=0;p<4;++p){
      int c = w + p*8;
      gld16(wcd + (size_t)(c*16 + (lane>>2))*768 + ki*32 + (lane&3)*8, &Bt[buf][c*512]);
    }
    if (w < 4){
      const u16* g;
      if (ki < 8) g = hsb + (size_t)(m0 + w*16 + (lane>>2))*ST  + ki*32 + (lane&3)*8;
      else        g = xb  + (size_t)(m0 + w*16 + (lane>>2))*HID + (ki-8)*32 + (lane&3)*8;
      gld16(g, &At[buf][w*512]);
    }
  };
  stage(0,0);
  __syncthreads();
  for (int ki=0; ki<24; ++ki){
    int buf = ki&1;
    if (ki < 23) stage(buf^1, ki+1);
    bf16x8 af[4], bfr[4];
    #pragma unroll
    for (int mi=0;mi<4;++mi)
      af[mi] = *(const bf16x8*)&At[buf][(mi*16 + l15)*32 + lg*8];
    #pragma unroll
    for (int ni=0;ni<4;++ni)
      bfr[ni] = *(const bf16x8*)&Bt[buf][(w*64 + ni*16 + l15)*32 + lg*8];
    #pragma unroll
    for (int mi=0;mi<4;++mi)
      #pragma unroll
      for (int ni=0;ni<4;++ni)
        acc[mi][ni] = __builtin_amdgcn_mfma_f32_16x16x32_bf16(af[mi], bfr[ni], acc[mi][ni], 0,0,0);
    __syncthreads();
  }
  // ---- epilogue: bias + residual + LayerNorm ----
  float g4[4], b4[4], bias4[4];
  #pragma unroll
  for (int ni=0;ni<4;++ni){
    int col = w*64 + ni*16 + l15;
    g4[ni] = gamma[col]; b4[ni] = beta[col]; bias4[ni] = biascd[col];
  }
  float psum[4][4] = {}, psq[4][4] = {};
  #pragma unroll
  for (int mi=0;mi<4;++mi)
    #pragma unroll
    for (int ni=0;ni<4;++ni)
      #pragma unroll
      for (int r=0;r<4;++r){
        int row = m0 + mi*16 + lg*4 + r;
        int col = w*64 + ni*16 + l15;
        float v = acc[mi][ni][r] + bias4[ni] + bf2f(xb[(size_t)row*HID + col]);
        acc[mi][ni][r] = v;
        psum[mi][r] += v; psq[mi][r] += v*v;
      }
  #pragma unroll
  for (int mi=0;mi<4;++mi)
    #pragma unroll
    for (int r=0;r<4;++r)
      #pragma unroll
      for (int d=1; d<16; d<<=1){
        psum[mi][r] += __shfl_xor(psum[mi][r], d);
        psq[mi][r]  += __shfl_xor(psq[mi][r], d);
      }
  if (l15 == 0){
    #pragma unroll
    for (int mi=0;mi<4;++mi)
      #pragma unroll
      for (int r=0;r<4;++r){
        int rl = mi*16 + lg*4 + r;
        redbuf[rl][w][0] = psum[mi][r];
        redbuf[rl][w][1] = psq[mi][r];
      }
  }
  __syncthreads();
  if (tid < 64){
    float s=0.f, q=0.f;
    #pragma unroll
    for (int wv=0; wv<8; ++wv){ s += redbuf[tid][wv][0]; q += redbuf[tid][wv][1]; }
    float mu = s*(1.f/512.f);
    float var = q*(1.f/512.f) - mu*mu;
    musig[tid][0] = mu;
    musig[tid][1] = rsqrtf(var + 1e-5f);
  }
  __syncthreads();
  #pragma unroll
  for (int mi=0;mi<4;++mi)
    #pragma unroll
    for (int r=0;r<4;++r){
      int rl = mi*16 + lg*4 + r;
      float mu = musig[rl][0], rs = musig[rl][1];
      #pragma unroll
      for (int ni=0;ni<4;++ni){
        int col = w*64 + ni*16 + l15;
        out[(size_t)(m0+rl)*HID + col] = (acc[mi][ni][r] - mu)*rs*g4[ni] + b4[ni];
      }
    }
}

// =====================================================================
extern "C" void kernel_launch(void* const* d_in, const int* in_sizes, int n_in,
                              void* d_out, int out_size, void* d_ws, size_t ws_size,
                              hipStream_t stream)
{
  const float* x     = (const float*)d_in[0];
  const float* A     = (const float*)d_in[1];
  const float* Wb    = (const float*)d_in[2];
  const float* bb    = (const float*)d_in[3];
  const float* Wc    = (const float*)d_in[4];
  const float* bc    = (const float*)d_in[5];
  const float* Wd    = (const float*)d_in[6];
  const float* bd    = (const float*)d_in[7];
  const float* gamma = (const float*)d_in[8];
  const float* beta  = (const float*)d_in[9];

  char* ws = (char*)d_ws;
  u16*   Ebf    = (u16*)  (ws + OFF_E);
  float* W32    = (float*)(ws + OFF_W32);
  u16*   wbb    = (u16*)  (ws + OFF_WB);
  u16*   wcdb   = (u16*)  (ws + OFF_WCD);
  float* biascd = (float*)(ws + OFF_BIAS);
  float* Rbuf   = (float*)(ws + OFF_R);
  float* Hc     = (float*)(ws + OFF_HC);
  u16*   ubuf   = (u16*)  (ws + OFF_U);
  u16*   hsb    = (u16*)  (ws + OFF_HS);
  u16*   xb     = (u16*)  (ws + OFF_XB);

  k_pe<<<2304, 256, 0, stream>>>(x, A, Wb, Wc, Wd, bc, bd, Ebf, W32, wbb, wcdb, biascd, xb);
  k_bx<<<512, 256, 0, stream>>>(xb, wbb, bb, ubuf);
  k_rec<false><<<64, 256, 0, stream>>>(Ebf, ubuf, nullptr, Rbuf, nullptr);
  k_scan<<<128, 256, 0, stream>>>(W32, Rbuf, Hc);
  k_rec<true><<<64, 256, 0, stream>>>(Ebf, ubuf, Hc, nullptr, hsb);
  k_out<<<512, 512, 0, stream>>>(hsb, xb, wcdb, biascd, gamma, beta, (float*)d_out);
}

// Round 2
// 384.801 us; speedup vs baseline: 1.0738x; 1.0738x over previous
//
#include <hip/hip_runtime.h>

#define HID 512
#define ST  256
#define BB  128
#define TT  256
#define BT  (BB*TT)
#define NCH 8
#define CHL 32

typedef unsigned short u16;
typedef unsigned int   u32;
typedef float f32x4  __attribute__((ext_vector_type(4)));
typedef __bf16 bf16x8 __attribute__((ext_vector_type(8)));

// ---- workspace layout (bytes) ----
#define OFF_E    0x0u        // 128 KB  E_hi = expm(A*DT)-I, bf16 [256][256]
#define OFF_EL   0x20000u    // 128 KB  E_lo = residual bf16 [256][256]
#define OFF_W32  0x40000u    // 256 KB  W32 fp32, W32[k*256+s] = Ad32[s][k]
#define OFF_WB   0x80000u    // 256 KB  Wb bf16 [256][512]
#define OFF_WCD  0xC0000u    // 768 KB  Wcd bf16 [512][768]  (k<256: Wc, k>=256: Wd)
#define OFF_BIAS 0x180000u   // 2 KB    bc+bd fp32 [512]
#define OFF_R    0x182000u   // 1 MB    R fp32 [8][128][256]
#define OFF_HC   0x282000u   // 1 MB    Hc fp32 [8][128][256]
#define OFF_U    0x400000u   // 16 MB   u bf16 [BT][256]
#define OFF_HS   0x1400000u  // 16 MB   hs bf16 [BT][256]
#define OFF_XB   0x2400000u  // 32 MB   x bf16 [BT][512]

__device__ __forceinline__ u16 f2bf(float f){
  u32 x = __float_as_uint(f);
  return (u16)((x + 0x7FFFu + ((x>>16)&1u)) >> 16);
}
__device__ __forceinline__ float bf2f(u16 u){
  return __uint_as_float(((u32)u)<<16);
}
__device__ __forceinline__ void gld16(const void* g, void* l){
  __builtin_amdgcn_global_load_lds((const __attribute__((address_space(1))) u32*)g,
                                   (__attribute__((address_space(3))) u32*)l, 16, 0, 0);
}

// =====================================================================
// k_pe: blocks [0,256): Ad Taylor (1 row per block, LDS-staged A slabs)
//       -> E_hi/E_lo bf16.  blocks [256,2304): prep (x->bf16, weights)
// =====================================================================
__global__ __launch_bounds__(256) void k_pe(
    const float* __restrict__ x, const float* __restrict__ A,
    const float* __restrict__ Wb, const float* __restrict__ Wc,
    const float* __restrict__ Wd, const float* __restrict__ bc,
    const float* __restrict__ bd, u16* __restrict__ Ebf,
    u16* __restrict__ Elo, u16* __restrict__ wbb,
    u16* __restrict__ wcdb, float* __restrict__ biascd,
    u16* __restrict__ xb)
{
  __shared__ float Ald[32*256];   // 32 KB slab of A rows
  __shared__ float cur[256];
  int bid = blockIdx.x;
  int tid = threadIdx.x;
  if (bid < 256){
    // ---- row `bid` of E = sum_{m>=1} (0.1A)^m / m! ----
    int c = tid, lane = tid & 63, w = tid >> 6;
    float a = A[(size_t)bid*256 + c] * 0.1f;
    float s = a;
    cur[c] = a;
    for (int m = 2; m <= 5; ++m){
      float ac0=0.f, ac1=0.f, ac2=0.f, ac3=0.f;
      for (int kb = 0; kb < 256; kb += 32){
        __syncthreads();                       // prior slab reads done
        #pragma unroll
        for (int r8 = 0; r8 < 8; ++r8)
          gld16(A + (size_t)kb*256 + r8*1024 + w*256 + lane*4,
                &Ald[r8*1024 + w*256]);
        __syncthreads();                       // drains vmcnt -> slab ready
        #pragma unroll
        for (int kk = 0; kk < 32; kk += 4){
          ac0 = fmaf(cur[kb+kk+0], Ald[(kk+0)*256 + c], ac0);
          ac1 = fmaf(cur[kb+kk+1], Ald[(kk+1)*256 + c], ac1);
          ac2 = fmaf(cur[kb+kk+2], Ald[(kk+2)*256 + c], ac2);
          ac3 = fmaf(cur[kb+kk+3], Ald[(kk+3)*256 + c], ac3);
        }
      }
      float n = ((ac0+ac1)+(ac2+ac3)) * (0.1f/(float)m);
      s += n;
      __syncthreads();
      cur[c] = n;
    }
    u16 hi = f2bf(s);
    Ebf[(size_t)bid*256 + c] = hi;
    Elo[(size_t)bid*256 + c] = f2bf(s - bf2f(hi));
    return;
  }
  // ---- prep (grid-stride over 2048 blocks) ----
  long gt = (long)(bid - 256)*256 + tid;
  const long np = 2048l*256l;
  for (long i = gt; i < (long)BT*HID/4; i += np){
    float4 v = ((const float4*)x)[i];
    u32 lo = (u32)f2bf(v.x) | ((u32)f2bf(v.y)<<16);
    u32 hi = (u32)f2bf(v.z) | ((u32)f2bf(v.w)<<16);
    uint2 q; q.x = lo; q.y = hi;
    ((uint2*)xb)[i] = q;
  }
  for (long i = gt; i < (long)ST*HID; i += np) wbb[i] = f2bf(Wb[i]);
  for (long i = gt; i < 512l*768l; i += np){
    int n = (int)(i/768), k = (int)(i%768);
    float v = (k < 256) ? Wc[n*256 + k] : Wd[n*512 + (k-256)];
    wcdb[i] = f2bf(v);
  }
  for (long i = gt; i < 512; i += np) biascd[i] = bc[i] + bd[i];
}

// =====================================================================
// k_bx: u[bt][s] = x_bf16 @ Wb^T + bb   (bf16 MFMA, m97-style)
// =====================================================================
__global__ __launch_bounds__(256,1) void k_bx(
    const u16* __restrict__ xb, const u16* __restrict__ wb,
    const float* __restrict__ bb, u16* __restrict__ uout)
{
  __shared__ u16 At[2][128*32];
  __shared__ u16 Bt[2][128*32];
  int bid = blockIdx.x;
  int m0 = (bid>>1)*128, n0 = (bid&1)*128;
  int tid = threadIdx.x, lane = tid&63, w = tid>>6, l15 = lane&15, lg = lane>>4;
  int wrow = (w>>1)*64, wcol = (w&1)*64;
  f32x4 acc[4][4] = {};

  auto stage = [&](int buf, int ki){
    #pragma unroll
    for (int p=0;p<2;++p){
      int c = w + p*4;
      int grow = c*16 + (lane>>2);
      int gk = ki*32 + (lane&3)*8;
      gld16(xb + (size_t)(m0+grow)*HID + gk, &At[buf][c*512]);
      gld16(wb + (size_t)(n0+grow)*HID + gk, &Bt[buf][c*512]);
    }
  };
  stage(0,0);
  __syncthreads();
  for (int ki=0; ki<16; ++ki){
    int buf = ki&1;
    if (ki < 15) stage(buf^1, ki+1);
    bf16x8 af[4], bfr[4];
    #pragma unroll
    for (int mi=0;mi<4;++mi)
      af[mi] = *(const bf16x8*)&At[buf][(wrow + mi*16 + l15)*32 + lg*8];
    #pragma unroll
    for (int ni=0;ni<4;++ni)
      bfr[ni] = *(const bf16x8*)&Bt[buf][(wcol + ni*16 + l15)*32 + lg*8];
    #pragma unroll
    for (int mi=0;mi<4;++mi)
      #pragma unroll
      for (int ni=0;ni<4;++ni)
        acc[mi][ni] = __builtin_amdgcn_mfma_f32_16x16x32_bf16(af[mi], bfr[ni], acc[mi][ni], 0,0,0);
    __syncthreads();
  }
  float bb4[4];
  #pragma unroll
  for (int ni=0;ni<4;++ni) bb4[ni] = bb[n0 + wcol + ni*16 + l15];
  #pragma unroll
  for (int mi=0;mi<4;++mi)
    #pragma unroll
    for (int ni=0;ni<4;++ni)
      #pragma unroll
      for (int r=0;r<4;++r){
        int row = m0 + wrow + mi*16 + lg*4 + r;
        int col = n0 + wcol + ni*16 + l15;
        uout[(size_t)row*ST + col] = f2bf(acc[mi][ni][r] + bb4[ni]);
      }
}

// =====================================================================
// k_rec: chunked recurrence  h_t = h_{t-1} + h_{t-1}@E^T (bf16 MFMA) + u_t
//   WRITE_HS=false: blocks [0,64): local pass, writes R[j]
//                   blocks [64,80): identity batch -> W32 = (Ad^32)^T
//                   (E_hi + E_lo double-MFMA for precision)
//   WRITE_HS=true : fixup pass from Hc[j], writes hs (bf16)
// =====================================================================
template<bool WRITE_HS>
__global__ __launch_bounds__(256,1) void k_rec(
    const u16* __restrict__ Ebf, const u16* __restrict__ Elo,
    const u16* __restrict__ ubuf, const float* __restrict__ Hc,
    float* __restrict__ Rbuf, u16* __restrict__ hsb,
    float* __restrict__ W32)
{
  int tid = threadIdx.x, lane = tid&63, w = tid>>6, l15 = lane&15, lg = lane>>4;
  __shared__ u16 hlds[2][16*256];

  if (!WRITE_HS && blockIdx.x >= 64){
    // ---- identity batch: W32[k][s] = Ad32[s][k] via 32 E-steps ----
    int b0 = ((int)blockIdx.x - 64)*16;
    bf16x8 ef[4][8], ef2[4][8];
    #pragma unroll
    for (int nt=0; nt<4; ++nt){
      int srow = w*64 + nt*16 + l15;
      #pragma unroll
      for (int kk=0; kk<8; ++kk){
        ef [nt][kk] = *(const bf16x8*)(Ebf + (size_t)srow*256 + kk*32 + lg*8);
        ef2[nt][kk] = *(const bf16x8*)(Elo + (size_t)srow*256 + kk*32 + lg*8);
      }
    }
    f32x4 acc[4];
    #pragma unroll
    for (int nt=0;nt<4;++nt)
      #pragma unroll
      for (int r=0;r<4;++r)
        acc[nt][r] = (b0 + lg*4 + r == w*64 + nt*16 + l15) ? 1.f : 0.f;
    for (int it=0; it<CHL; ++it){
      u16* hb = hlds[it&1];
      #pragma unroll
      for (int nt=0;nt<4;++nt)
        #pragma unroll
        for (int r=0;r<4;++r){
          int row = lg*4 + r;
          int sc  = w*64 + nt*16 + l15;
          int off = (row*512 + sc*2) ^ ((row&7)<<4);
          hb[off>>1] = f2bf(acc[nt][r]);
        }
      __syncthreads();
      bf16x8 af[8];
      #pragma unroll
      for (int kk=0;kk<8;++kk){
        int off = (l15*512 + (kk*32 + lg*8)*2) ^ ((l15&7)<<4);
        af[kk] = *(const bf16x8*)(hb + (off>>1));
      }
      #pragma unroll
      for (int nt=0;nt<4;++nt)
        #pragma unroll
        for (int kk=0;kk<8;++kk)
          acc[nt] = __builtin_amdgcn_mfma_f32_16x16x32_bf16(af[kk], ef[nt][kk], acc[nt], 0,0,0);
      #pragma unroll
      for (int nt=0;nt<4;++nt)
        #pragma unroll
        for (int kk=0;kk<8;++kk)
          acc[nt] = __builtin_amdgcn_mfma_f32_16x16x32_bf16(af[kk], ef2[nt][kk], acc[nt], 0,0,0);
    }
    #pragma unroll
    for (int nt=0;nt<4;++nt)
      #pragma unroll
      for (int r=0;r<4;++r)
        W32[(size_t)(b0 + lg*4 + r)*256 + w*64 + nt*16 + l15] = acc[nt][r];
    return;
  }

  // ---- main recurrence path ----
  int j = (int)blockIdx.x >> 3;
  int b0 = ((int)blockIdx.x & 7)*16;

  bf16x8 ef[4][8];
  #pragma unroll
  for (int nt=0; nt<4; ++nt){
    int srow = w*64 + nt*16 + l15;
    #pragma unroll
    for (int kk=0; kk<8; ++kk)
      ef[nt][kk] = *(const bf16x8*)(Ebf + (size_t)srow*256 + kk*32 + lg*8);
  }

  f32x4 acc[4];
  #pragma unroll
  for (int nt=0;nt<4;++nt){
    if (WRITE_HS && j > 0){
      #pragma unroll
      for (int r=0;r<4;++r)
        acc[nt][r] = Hc[((size_t)j*BB + b0 + lg*4 + r)*ST + w*64 + nt*16 + l15];
    } else {
      acc[nt] = (f32x4){0.f,0.f,0.f,0.f};
    }
  }

  int t0 = j*CHL;
  // prefetch u[t0]
  float uv[4][4];
  #pragma unroll
  for (int nt=0;nt<4;++nt)
    #pragma unroll
    for (int r=0;r<4;++r)
      uv[nt][r] = bf2f(ubuf[((size_t)(b0 + lg*4 + r)*TT + t0)*ST + w*64 + nt*16 + l15]);

  for (int it=0; it<CHL; ++it){
    int t = t0 + it;
    // stage h_{t-1} (bf16, XOR-swizzled) into double-buffered LDS
    u16* hb = hlds[it&1];
    #pragma unroll
    for (int nt=0;nt<4;++nt)
      #pragma unroll
      for (int r=0;r<4;++r){
        int row = lg*4 + r;
        int sc  = w*64 + nt*16 + l15;
        int off = (row*512 + sc*2) ^ ((row&7)<<4);
        hb[off>>1] = f2bf(acc[nt][r]);
      }
    __syncthreads();
    // prefetch u[t+1] (used next iteration; latency hides under MFMA)
    float uvn[4][4];
    if (it+1 < CHL){
      #pragma unroll
      for (int nt=0;nt<4;++nt)
        #pragma unroll
        for (int r=0;r<4;++r)
          uvn[nt][r] = bf2f(ubuf[((size_t)(b0 + lg*4 + r)*TT + t + 1)*ST + w*64 + nt*16 + l15]);
    }
    // A-fragments of h_{t-1}
    bf16x8 af[8];
    #pragma unroll
    for (int kk=0;kk<8;++kk){
      int off = (l15*512 + (kk*32 + lg*8)*2) ^ ((l15&7)<<4);
      af[kk] = *(const bf16x8*)(hb + (off>>1));
    }
    // h += h@E^T
    #pragma unroll
    for (int nt=0;nt<4;++nt)
      #pragma unroll
      for (int kk=0;kk<8;++kk)
        acc[nt] = __builtin_amdgcn_mfma_f32_16x16x32_bf16(af[kk], ef[nt][kk], acc[nt], 0,0,0);
    // h += u_t (fp32 carry)
    #pragma unroll
    for (int nt=0;nt<4;++nt)
      #pragma unroll
      for (int r=0;r<4;++r)
        acc[nt][r] += uv[nt][r];
    if (WRITE_HS){
      #pragma unroll
      for (int nt=0;nt<4;++nt)
        #pragma unroll
        for (int r=0;r<4;++r)
          hsb[((size_t)(b0 + lg*4 + r)*TT + t)*ST + w*64 + nt*16 + l15] = f2bf(acc[nt][r]);
    }
    if (it+1 < CHL){
      #pragma unroll
      for (int nt=0;nt<4;++nt)
        #pragma unroll
        for (int r=0;r<4;++r)
          uv[nt][r] = uvn[nt][r];
    }
  }
  if (!WRITE_HS){
    #pragma unroll
    for (int nt=0;nt<4;++nt)
      #pragma unroll
      for (int r=0;r<4;++r)
        Rbuf[((size_t)j*BB + b0 + lg*4 + r)*ST + w*64 + nt*16 + l15] = acc[nt][r];
  }
}

// =====================================================================
// k_scan: chunk-carry scan (fp32):  H_1 = R_0;  H_j = H_{j-1}@Ad32^T + R_{j-1}
// =====================================================================
__global__ __launch_bounds__(256) void k_scan(
    const float* __restrict__ W32, const float* __restrict__ Rbuf,
    float* __restrict__ Hc)
{
  int b = blockIdx.x;
  int s = threadIdx.x;
  __shared__ float hp[256];
  float h = Rbuf[(size_t)(0*BB + b)*ST + s];
  Hc[(size_t)(1*BB + b)*ST + s] = h;
  for (int j = 2; j < NCH; ++j){
    hp[s] = h;
    __syncthreads();
    float a = Rbuf[(size_t)((j-1)*BB + b)*ST + s];
    #pragma unroll 4
    for (int k=0;k<256;++k)
      a = fmaf(hp[k], W32[(size_t)k*256 + s], a);
    __syncthreads();
    h = a;
    Hc[(size_t)j*BB*ST + (size_t)b*ST + s] = h;
  }
}

// =====================================================================
// k_out: out = LN( hs@Wc^T + x@Wd^T + bc + bd + x ) * gamma + beta
// =====================================================================
__global__ __launch_bounds__(512,2) void k_out(
    const u16* __restrict__ hsb, const u16* __restrict__ xb,
    const u16* __restrict__ wcd, const float* __restrict__ biascd,
    const float* __restrict__ gamma, const float* __restrict__ beta,
    float* __restrict__ out)
{
  __shared__ u16 At[2][64*32];
  __shared__ u16 Bt[2][512*32];
  __shared__ float redbuf[64][8][2];
  __shared__ float musig[64][2];
  int m0 = blockIdx.x*64;
  int tid = threadIdx.x, lane = tid&63, w = tid>>6, l15 = lane&15, lg = lane>>4;
  f32x4 acc[4][4] = {};

  auto stage = [&](int buf, int ki){
    #pragma unroll
    for (int p=0;p<4;++p){
      int c = w + p*8;
      gld16(wcd + (size_t)(c*16 + (lane>>2))*768 + ki*32 + (lane&3)*8, &Bt[buf][c*512]);
    }
    if (w < 4){
      const u16* g;
      if (ki < 8) g = hsb + (size_t)(m0 + w*16 + (lane>>2))*ST  + ki*32 + (lane&3)*8;
      else        g = xb  + (size_t)(m0 + w*16 + (lane>>2))*HID + (ki-8)*32 + (lane&3)*8;
      gld16(g, &At[buf][w*512]);
    }
  };
  stage(0,0);
  __syncthreads();
  for (int ki=0; ki<24; ++ki){
    int buf = ki&1;
    if (ki < 23) stage(buf^1, ki+1);
    bf16x8 af[4], bfr[4];
    #pragma unroll
    for (int mi=0;mi<4;++mi)
      af[mi] = *(const bf16x8*)&At[buf][(mi*16 + l15)*32 + lg*8];
    #pragma unroll
    for (int ni=0;ni<4;++ni)
      bfr[ni] = *(const bf16x8*)&Bt[buf][(w*64 + ni*16 + l15)*32 + lg*8];
    #pragma unroll
    for (int mi=0;mi<4;++mi)
      #pragma unroll
      for (int ni=0;ni<4;++ni)
        acc[mi][ni] = __builtin_amdgcn_mfma_f32_16x16x32_bf16(af[mi], bfr[ni], acc[mi][ni], 0,0,0);
    __syncthreads();
  }
  // ---- epilogue: bias + residual + LayerNorm ----
  float g4[4], b4[4], bias4[4];
  #pragma unroll
  for (int ni=0;ni<4;++ni){
    int col = w*64 + ni*16 + l15;
    g4[ni] = gamma[col]; b4[ni] = beta[col]; bias4[ni] = biascd[col];
  }
  float psum[4][4] = {}, psq[4][4] = {};
  #pragma unroll
  for (int mi=0;mi<4;++mi)
    #pragma unroll
    for (int ni=0;ni<4;++ni)
      #pragma unroll
      for (int r=0;r<4;++r){
        int row = m0 + mi*16 + lg*4 + r;
        int col = w*64 + ni*16 + l15;
        float v = acc[mi][ni][r] + bias4[ni] + bf2f(xb[(size_t)row*HID + col]);
        acc[mi][ni][r] = v;
        psum[mi][r] += v; psq[mi][r] += v*v;
      }
  #pragma unroll
  for (int mi=0;mi<4;++mi)
    #pragma unroll
    for (int r=0;r<4;++r)
      #pragma unroll
      for (int d=1; d<16; d<<=1){
        psum[mi][r] += __shfl_xor(psum[mi][r], d);
        psq[mi][r]  += __shfl_xor(psq[mi][r], d);
      }
  if (l15 == 0){
    #pragma unroll
    for (int mi=0;mi<4;++mi)
      #pragma unroll
      for (int r=0;r<4;++r){
        int rl = mi*16 + lg*4 + r;
        redbuf[rl][w][0] = psum[mi][r];
        redbuf[rl][w][1] = psq[mi][r];
      }
  }
  __syncthreads();
  if (tid < 64){
    float s=0.f, q=0.f;
    #pragma unroll
    for (int wv=0; wv<8; ++wv){ s += redbuf[tid][wv][0]; q += redbuf[tid][wv][1]; }
    float mu = s*(1.f/512.f);
    float var = q*(1.f/512.f) - mu*mu;
    musig[tid][0] = mu;
    musig[tid][1] = rsqrtf(var + 1e-5f);
  }
  __syncthreads();
  #pragma unroll
  for (int mi=0;mi<4;++mi)
    #pragma unroll
    for (int r=0;r<4;++r){
      int rl = mi*16 + lg*4 + r;
      float mu = musig[rl][0], rs = musig[rl][1];
      #pragma unroll
      for (int ni=0;ni<4;++ni){
        int col = w*64 + ni*16 + l15;
        out[(size_t)(m0+rl)*HID + col] = (acc[mi][ni][r] - mu)*rs*g4[ni] + b4[ni];
      }
    }
}

// =====================================================================
extern "C" void kernel_launch(void* const* d_in, const int* in_sizes, int n_in,
                              void* d_out, int out_size, void* d_ws, size_t ws_size,
                              hipStream_t stream)
{
  const float* x     = (const float*)d_in[0];
  const float* A     = (const float*)d_in[1];
  const float* Wb    = (const float*)d_in[2];
  const float* bb    = (const float*)d_in[3];
  const float* Wc    = (const float*)d_in[4];
  const float* bc    = (const float*)d_in[5];
  const float* Wd    = (const float*)d_in[6];
  const float* bd    = (const float*)d_in[7];
  const float* gamma = (const float*)d_in[8];
  const float* beta  = (const float*)d_in[9];

  char* ws = (char*)d_ws;
  u16*   Ebf    = (u16*)  (ws + OFF_E);
  u16*   Elo    = (u16*)  (ws + OFF_EL);
  float* W32    = (float*)(ws + OFF_W32);
  u16*   wbb    = (u16*)  (ws + OFF_WB);
  u16*   wcdb   = (u16*)  (ws + OFF_WCD);
  float* biascd = (float*)(ws + OFF_BIAS);
  float* Rbuf   = (float*)(ws + OFF_R);
  float* Hc     = (float*)(ws + OFF_HC);
  u16*   ubuf   = (u16*)  (ws + OFF_U);
  u16*   hsb    = (u16*)  (ws + OFF_HS);
  u16*   xb     = (u16*)  (ws + OFF_XB);

  k_pe<<<2304, 256, 0, stream>>>(x, A, Wb, Wc, Wd, bc, bd, Ebf, Elo, wbb, wcdb, biascd, xb);
  k_bx<<<512, 256, 0, stream>>>(xb, wbb, bb, ubuf);
  k_rec<false><<<80, 256, 0, stream>>>(Ebf, Elo, ubuf, nullptr, Rbuf, nullptr, W32);
  k_scan<<<128, 256, 0, stream>>>(W32, Rbuf, Hc);
  k_rec<true><<<64, 256, 0, stream>>>(Ebf, Elo, ubuf, Hc, nullptr, hsb, W32);
  k_out<<<512, 512, 0, stream>>>(hsb, xb, wcdb, biascd, gamma, beta, (float*)d_out);
}

// Round 4
// 348.030 us; speedup vs baseline: 1.1872x; 1.1057x over previous
//
#include <hip/hip_runtime.h>

#define HID 512
#define ST  256
#define BB  128
#define TT  256
#define BT  (BB*TT)
#define NCH 8
#define CHL 32

typedef unsigned short u16;
typedef unsigned int   u32;
typedef float f32x4  __attribute__((ext_vector_type(4)));
typedef __bf16 bf16x8 __attribute__((ext_vector_type(8)));

// ---- workspace layout (bytes) ----
#define OFF_E    0x0u        // 128 KB  E_hi = expm(A*DT)-I, bf16 [256][256]
#define OFF_EL   0x20000u    // 128 KB  E_lo = residual bf16 [256][256]
#define OFF_W32  0x40000u    // 256 KB  W32 fp32, W32[k*256+s] = Ad32[s][k]
#define OFF_WB   0x80000u    // 256 KB  Wb bf16 [256][512]
#define OFF_WCD  0xC0000u    // 768 KB  Wcd bf16 [512][768]  (k<256: Wc, k>=256: Wd)
#define OFF_BIAS 0x180000u   // 2 KB    bc+bd fp32 [512]
#define OFF_R    0x182000u   // 1 MB    R fp32 [8][128][256]
#define OFF_HC   0x282000u   // 1 MB    Hc fp32 [8][128][256]
#define OFF_MH   0x390000u   // 128 KB  M_hi bf16 (M = 0.1*A)
#define OFF_ML   0x3B0000u   // 128 KB  M_lo bf16
#define OFF_U    0x400000u   // 16 MB   u bf16 [BT][256]
#define OFF_HS   0x1400000u  // 16 MB   hs bf16 [BT][256]
#define OFF_XB   0x2400000u  // 32 MB   x bf16 [BT][512]

__device__ __forceinline__ u16 f2bf(float f){
  u32 x = __float_as_uint(f);
  return (u16)((x + 0x7FFFu + ((x>>16)&1u)) >> 16);
}
__device__ __forceinline__ float bf2f(u16 u){
  return __uint_as_float(((u32)u)<<16);
}
__device__ __forceinline__ void gld16(const void* g, void* l){
  __builtin_amdgcn_global_load_lds((const __attribute__((address_space(1))) u32*)g,
                                   (__attribute__((address_space(3))) u32*)l, 16, 0, 0);
}

// =====================================================================
// k_pe: pure prep, no LDS, full occupancy.
//   x->bf16, Wb->bf16, Wcd pack, bias, M=0.1A -> hi/lo bf16 split
// =====================================================================
__global__ __launch_bounds__(256) void k_pe(
    const float* __restrict__ x, const float* __restrict__ A,
    const float* __restrict__ Wb, const float* __restrict__ Wc,
    const float* __restrict__ Wd, const float* __restrict__ bc,
    const float* __restrict__ bd, u16* __restrict__ Mhi,
    u16* __restrict__ Mlo, u16* __restrict__ wbb,
    u16* __restrict__ wcdb, float* __restrict__ biascd,
    u16* __restrict__ xb)
{
  long gt = (long)blockIdx.x*256 + threadIdx.x;
  const long np = 2048l*256l;
  for (long i = gt; i < (long)BT*HID/4; i += np){
    float4 v = ((const float4*)x)[i];
    u32 lo = (u32)f2bf(v.x) | ((u32)f2bf(v.y)<<16);
    u32 hi = (u32)f2bf(v.z) | ((u32)f2bf(v.w)<<16);
    uint2 q; q.x = lo; q.y = hi;
    ((uint2*)xb)[i] = q;
  }
  for (long i = gt; i < (long)ST*HID; i += np) wbb[i] = f2bf(Wb[i]);
  for (long i = gt; i < 512l*256l; i += np)
    wcdb[(size_t)(i>>8)*768 + (i&255)] = f2bf(Wc[i]);
  for (long i = gt; i < 512l*512l; i += np)
    wcdb[(size_t)(i>>9)*768 + 256 + (i&511)] = f2bf(Wd[i]);
  for (long i = gt; i < 256l*256l; i += np){
    float m = A[i]*0.1f;
    u16 h = f2bf(m);
    Mhi[i] = h;
    Mlo[i] = f2bf(m - bf2f(h));
  }
  for (long i = gt; i < 512; i += np) biascd[i] = bc[i] + bd[i];
}

// =====================================================================
// k_expm: E = M + M^2/2 + M^3/6 (elementwise M^4/24 ~2e-10 << E_lo lsb)
// Column-partitioned: block bn owns cols J=[bn*16,bn*16+16); products are
// matrix-vector chains on those columns -> no cross-block deps.
// M as A-fragments direct from global (bf16 hi/lo); V staged in LDS.
// =====================================================================
__global__ __launch_bounds__(256,1) void k_expm(
    const float* __restrict__ A, const u16* __restrict__ Mhi,
    const u16* __restrict__ Mlo, u16* __restrict__ Ebf,
    u16* __restrict__ Elo)
{
  __shared__ u16 V1h[16*256], V1l[16*256], V2h[16*256];
  int bn = blockIdx.x;
  int tid = threadIdx.x, lane = tid&63, w = tid>>6, l15 = lane&15, lg = lane>>4;
  int j = bn*16 + l15;
  // V1 = M[:,J] in C-layout regs; stage transposed (hi/lo) into LDS
  float v1[4][4];
  #pragma unroll
  for (int mi=0;mi<4;++mi)
    #pragma unroll
    for (int r=0;r<4;++r){
      int i = w*64 + mi*16 + lg*4 + r;
      float v = 0.1f * A[(size_t)i*256 + j];
      v1[mi][r] = v;
      u16 h = f2bf(v);
      int off = (l15*512 + i*2) ^ ((l15&7)<<4);
      V1h[off>>1] = h;
      V1l[off>>1] = f2bf(v - bf2f(h));
    }
  __syncthreads();
  // V2 = M*V1  (3-pass hi/lo for ~1e-5 relative)
  f32x4 a2[4] = {};
  #pragma unroll
  for (int kk=0;kk<8;++kk){
    int boff = (l15*512 + (kk*32 + lg*8)*2) ^ ((l15&7)<<4);
    bf16x8 bh = *(const bf16x8*)(V1h + (boff>>1));
    bf16x8 bl = *(const bf16x8*)(V1l + (boff>>1));
    #pragma unroll
    for (int mi=0;mi<4;++mi){
      size_t ro = (size_t)(w*64 + mi*16 + l15)*256 + kk*32 + lg*8;
      bf16x8 ah = *(const bf16x8*)(Mhi + ro);
      bf16x8 al = *(const bf16x8*)(Mlo + ro);
      a2[mi] = __builtin_amdgcn_mfma_f32_16x16x32_bf16(ah, bh, a2[mi],0,0,0);
      a2[mi] = __builtin_amdgcn_mfma_f32_16x16x32_bf16(ah, bl, a2[mi],0,0,0);
      a2[mi] = __builtin_amdgcn_mfma_f32_16x16x32_bf16(al, bh, a2[mi],0,0,0);
    }
  }
  // stage V2 (hi only; V3 term needs only ~1e-2 relative)
  #pragma unroll
  for (int mi=0;mi<4;++mi)
    #pragma unroll
    for (int r=0;r<4;++r){
      int i = w*64 + mi*16 + lg*4 + r;
      int off = (l15*512 + i*2) ^ ((l15&7)<<4);
      V2h[off>>1] = f2bf(a2[mi][r]);
    }
  __syncthreads();
  // V3 = M*V2 (single pass)
  f32x4 a3[4] = {};
  #pragma unroll
  for (int kk=0;kk<8;++kk){
    int boff = (l15*512 + (kk*32 + lg*8)*2) ^ ((l15&7)<<4);
    bf16x8 bh = *(const bf16x8*)(V2h + (boff>>1));
    #pragma unroll
    for (int mi=0;mi<4;++mi){
      bf16x8 ah = *(const bf16x8*)(Mhi + (size_t)(w*64 + mi*16 + l15)*256 + kk*32 + lg*8);
      a3[mi] = __builtin_amdgcn_mfma_f32_16x16x32_bf16(ah, bh, a3[mi],0,0,0);
    }
  }
  // E = V1 + V2/2 + V3/6 -> hi/lo
  #pragma unroll
  for (int mi=0;mi<4;++mi)
    #pragma unroll
    for (int r=0;r<4;++r){
      int i = w*64 + mi*16 + lg*4 + r;
      float s = v1[mi][r] + 0.5f*a2[mi][r] + (1.f/6.f)*a3[mi][r];
      u16 h = f2bf(s);
      Ebf[(size_t)i*256 + j] = h;
      Elo[(size_t)i*256 + j] = f2bf(s - bf2f(h));
    }
}

// =====================================================================
// k_bx: u[bt][s] = x_bf16 @ Wb^T + bb   (bf16 MFMA, m97-style)
// =====================================================================
__global__ __launch_bounds__(256,1) void k_bx(
    const u16* __restrict__ xb, const u16* __restrict__ wb,
    const float* __restrict__ bb, u16* __restrict__ uout)
{
  __shared__ u16 At[2][128*32];
  __shared__ u16 Bt[2][128*32];
  int bid = blockIdx.x;
  int m0 = (bid>>1)*128, n0 = (bid&1)*128;
  int tid = threadIdx.x, lane = tid&63, w = tid>>6, l15 = lane&15, lg = lane>>4;
  int wrow = (w>>1)*64, wcol = (w&1)*64;
  f32x4 acc[4][4] = {};

  auto stage = [&](int buf, int ki){
    #pragma unroll
    for (int p=0;p<2;++p){
      int c = w + p*4;
      int grow = c*16 + (lane>>2);
      int gk = ki*32 + (lane&3)*8;
      gld16(xb + (size_t)(m0+grow)*HID + gk, &At[buf][c*512]);
      gld16(wb + (size_t)(n0+grow)*HID + gk, &Bt[buf][c*512]);
    }
  };
  stage(0,0);
  __syncthreads();
  for (int ki=0; ki<16; ++ki){
    int buf = ki&1;
    if (ki < 15) stage(buf^1, ki+1);
    bf16x8 af[4], bfr[4];
    #pragma unroll
    for (int mi=0;mi<4;++mi)
      af[mi] = *(const bf16x8*)&At[buf][(wrow + mi*16 + l15)*32 + lg*8];
    #pragma unroll
    for (int ni=0;ni<4;++ni)
      bfr[ni] = *(const bf16x8*)&Bt[buf][(wcol + ni*16 + l15)*32 + lg*8];
    #pragma unroll
    for (int mi=0;mi<4;++mi)
      #pragma unroll
      for (int ni=0;ni<4;++ni)
        acc[mi][ni] = __builtin_amdgcn_mfma_f32_16x16x32_bf16(af[mi], bfr[ni], acc[mi][ni], 0,0,0);
    __syncthreads();
  }
  float bb4[4];
  #pragma unroll
  for (int ni=0;ni<4;++ni) bb4[ni] = bb[n0 + wcol + ni*16 + l15];
  #pragma unroll
  for (int mi=0;mi<4;++mi)
    #pragma unroll
    for (int ni=0;ni<4;++ni)
      #pragma unroll
      for (int r=0;r<4;++r){
        int row = m0 + wrow + mi*16 + lg*4 + r;
        int col = n0 + wcol + ni*16 + l15;
        uout[(size_t)row*ST + col] = f2bf(acc[mi][ni][r] + bb4[ni]);
      }
}

// =====================================================================
// k_rec: chunked recurrence  h_t = h_{t-1} + h_{t-1}@E^T (bf16 MFMA) + u_t
//   WRITE_HS=false: blocks [0,64): local pass, writes R[j]
//                   blocks [64,80): identity batch -> W32 = (Ad^32)^T
//   WRITE_HS=true : fixup pass from Hc[j], writes hs (bf16)
// =====================================================================
template<bool WRITE_HS>
__global__ __launch_bounds__(256,1) void k_rec(
    const u16* __restrict__ Ebf, const u16* __restrict__ Elo,
    const u16* __restrict__ ubuf, const float* __restrict__ Hc,
    float* __restrict__ Rbuf, u16* __restrict__ hsb,
    float* __restrict__ W32)
{
  int tid = threadIdx.x, lane = tid&63, w = tid>>6, l15 = lane&15, lg = lane>>4;
  __shared__ u16 hlds[2][16*256];

  if (!WRITE_HS && blockIdx.x >= 64){
    // ---- identity batch: W32[k][s] = Ad32[s][k] via 32 E-steps ----
    int b0 = ((int)blockIdx.x - 64)*16;
    bf16x8 ef[4][8], ef2[4][8];
    #pragma unroll
    for (int nt=0; nt<4; ++nt){
      int srow = w*64 + nt*16 + l15;
      #pragma unroll
      for (int kk=0; kk<8; ++kk){
        ef [nt][kk] = *(const bf16x8*)(Ebf + (size_t)srow*256 + kk*32 + lg*8);
        ef2[nt][kk] = *(const bf16x8*)(Elo + (size_t)srow*256 + kk*32 + lg*8);
      }
    }
    f32x4 acc[4];
    #pragma unroll
    for (int nt=0;nt<4;++nt)
      #pragma unroll
      for (int r=0;r<4;++r)
        acc[nt][r] = (b0 + lg*4 + r == w*64 + nt*16 + l15) ? 1.f : 0.f;
    for (int it=0; it<CHL; ++it){
      u16* hb = hlds[it&1];
      #pragma unroll
      for (int nt=0;nt<4;++nt)
        #pragma unroll
        for (int r=0;r<4;++r){
          int row = lg*4 + r;
          int sc  = w*64 + nt*16 + l15;
          int off = (row*512 + sc*2) ^ ((row&7)<<4);
          hb[off>>1] = f2bf(acc[nt][r]);
        }
      __syncthreads();
      bf16x8 af[8];
      #pragma unroll
      for (int kk=0;kk<8;++kk){
        int off = (l15*512 + (kk*32 + lg*8)*2) ^ ((l15&7)<<4);
        af[kk] = *(const bf16x8*)(hb + (off>>1));
      }
      #pragma unroll
      for (int nt=0;nt<4;++nt)
        #pragma unroll
        for (int kk=0;kk<8;++kk)
          acc[nt] = __builtin_amdgcn_mfma_f32_16x16x32_bf16(af[kk], ef[nt][kk], acc[nt], 0,0,0);
      #pragma unroll
      for (int nt=0;nt<4;++nt)
        #pragma unroll
        for (int kk=0;kk<8;++kk)
          acc[nt] = __builtin_amdgcn_mfma_f32_16x16x32_bf16(af[kk], ef2[nt][kk], acc[nt], 0,0,0);
    }
    #pragma unroll
    for (int nt=0;nt<4;++nt)
      #pragma unroll
      for (int r=0;r<4;++r)
        W32[(size_t)(b0 + lg*4 + r)*256 + w*64 + nt*16 + l15] = acc[nt][r];
    return;
  }

  // ---- main recurrence path ----
  int j = (int)blockIdx.x >> 3;
  int b0 = ((int)blockIdx.x & 7)*16;

  bf16x8 ef[4][8];
  #pragma unroll
  for (int nt=0; nt<4; ++nt){
    int srow = w*64 + nt*16 + l15;
    #pragma unroll
    for (int kk=0; kk<8; ++kk)
      ef[nt][kk] = *(const bf16x8*)(Ebf + (size_t)srow*256 + kk*32 + lg*8);
  }

  f32x4 acc[4];
  #pragma unroll
  for (int nt=0;nt<4;++nt){
    if (WRITE_HS && j > 0){
      #pragma unroll
      for (int r=0;r<4;++r)
        acc[nt][r] = Hc[((size_t)j*BB + b0 + lg*4 + r)*ST + w*64 + nt*16 + l15];
    } else {
      acc[nt] = (f32x4){0.f,0.f,0.f,0.f};
    }
  }

  int t0 = j*CHL;
  // prefetch u[t0]
  float uv[4][4];
  #pragma unroll
  for (int nt=0;nt<4;++nt)
    #pragma unroll
    for (int r=0;r<4;++r)
      uv[nt][r] = bf2f(ubuf[((size_t)(b0 + lg*4 + r)*TT + t0)*ST + w*64 + nt*16 + l15]);

  for (int it=0; it<CHL; ++it){
    int t = t0 + it;
    // stage h_{t-1} (bf16, XOR-swizzled) into double-buffered LDS
    u16* hb = hlds[it&1];
    #pragma unroll
    for (int nt=0;nt<4;++nt)
      #pragma unroll
      for (int r=0;r<4;++r){
        int row = lg*4 + r;
        int sc  = w*64 + nt*16 + l15;
        int off = (row*512 + sc*2) ^ ((row&7)<<4);
        hb[off>>1] = f2bf(acc[nt][r]);
      }
    __syncthreads();
    // prefetch u[t+1] (latency hides under MFMA)
    float uvn[4][4];
    if (it+1 < CHL){
      #pragma unroll
      for (int nt=0;nt<4;++nt)
        #pragma unroll
        for (int r=0;r<4;++r)
          uvn[nt][r] = bf2f(ubuf[((size_t)(b0 + lg*4 + r)*TT + t + 1)*ST + w*64 + nt*16 + l15]);
    }
    // A-fragments of h_{t-1}
    bf16x8 af[8];
    #pragma unroll
    for (int kk=0;kk<8;++kk){
      int off = (l15*512 + (kk*32 + lg*8)*2) ^ ((l15&7)<<4);
      af[kk] = *(const bf16x8*)(hb + (off>>1));
    }
    // h += h@E^T
    #pragma unroll
    for (int nt=0;nt<4;++nt)
      #pragma unroll
      for (int kk=0;kk<8;++kk)
        acc[nt] = __builtin_amdgcn_mfma_f32_16x16x32_bf16(af[kk], ef[nt][kk], acc[nt], 0,0,0);
    // h += u_t (fp32 carry)
    #pragma unroll
    for (int nt=0;nt<4;++nt)
      #pragma unroll
      for (int r=0;r<4;++r)
        acc[nt][r] += uv[nt][r];
    if (WRITE_HS){
      #pragma unroll
      for (int nt=0;nt<4;++nt)
        #pragma unroll
        for (int r=0;r<4;++r)
          hsb[((size_t)(b0 + lg*4 + r)*TT + t)*ST + w*64 + nt*16 + l15] = f2bf(acc[nt][r]);
    }
    if (it+1 < CHL){
      #pragma unroll
      for (int nt=0;nt<4;++nt)
        #pragma unroll
        for (int r=0;r<4;++r)
          uv[nt][r] = uvn[nt][r];
    }
  }
  if (!WRITE_HS){
    #pragma unroll
    for (int nt=0;nt<4;++nt)
      #pragma unroll
      for (int r=0;r<4;++r)
        Rbuf[((size_t)j*BB + b0 + lg*4 + r)*ST + w*64 + nt*16 + l15] = acc[nt][r];
  }
}

// =====================================================================
// k_scan: chunk-carry scan (fp32):  H_1 = R_0;  H_j = H_{j-1}@Ad32^T + R_{j-1}
// =====================================================================
__global__ __launch_bounds__(256) void k_scan(
    const float* __restrict__ W32, const float* __restrict__ Rbuf,
    float* __restrict__ Hc)
{
  int b = blockIdx.x;
  int s = threadIdx.x;
  __shared__ float hp[256];
  float h = Rbuf[(size_t)(0*BB + b)*ST + s];
  Hc[(size_t)(1*BB + b)*ST + s] = h;
  for (int j = 2; j < NCH; ++j){
    hp[s] = h;
    __syncthreads();
    float a = Rbuf[(size_t)((j-1)*BB + b)*ST + s];
    #pragma unroll 4
    for (int k=0;k<256;++k)
      a = fmaf(hp[k], W32[(size_t)k*256 + s], a);
    __syncthreads();
    h = a;
    Hc[(size_t)j*BB*ST + (size_t)b*ST + s] = h;
  }
}

// =====================================================================
// k_out: out = LN( hs@Wc^T + x@Wd^T + bc + bd + x ) * gamma + beta
// =====================================================================
__global__ __launch_bounds__(512,2) void k_out(
    const u16* __restrict__ hsb, const u16* __restrict__ xb,
    const u16* __restrict__ wcd, const float* __restrict__ biascd,
    const float* __restrict__ gamma, const float* __restrict__ beta,
    float* __restrict__ out)
{
  __shared__ u16 At[2][64*32];
  __shared__ u16 Bt[2][512*32];
  __shared__ float redbuf[64][8][2];
  __shared__ float musig[64][2];
  int m0 = blockIdx.x*64;
  int tid = threadIdx.x, lane = tid&63, w = tid>>6, l15 = lane&15, lg = lane>>4;
  f32x4 acc[4][4] = {};

  auto stage = [&](int buf, int ki){
    #pragma unroll
    for (int p=0;p<4;++p){
      int c = w + p*8;
      gld16(wcd + (size_t)(c*16 + (lane>>2))*768 + ki*32 + (lane&3)*8, &Bt[buf][c*512]);
    }
    if (w < 4){
      const u16* g;
      if (ki < 8) g = hsb + (size_t)(m0 + w*16 + (lane>>2))*ST  + ki*32 + (lane&3)*8;
      else        g = xb  + (size_t)(m0 + w*16 + (lane>>2))*HID + (ki-8)*32 + (lane&3)*8;
      gld16(g, &At[buf][w*512]);
    }
  };
  stage(0,0);
  __syncthreads();
  for (int ki=0; ki<24; ++ki){
    int buf = ki&1;
    if (ki < 23) stage(buf^1, ki+1);
    bf16x8 af[4], bfr[4];
    #pragma unroll
    for (int mi=0;mi<4;++mi)
      af[mi] = *(const bf16x8*)&At[buf][(mi*16 + l15)*32 + lg*8];
    #pragma unroll
    for (int ni=0;ni<4;++ni)
      bfr[ni] = *(const bf16x8*)&Bt[buf][(w*64 + ni*16 + l15)*32 + lg*8];
    #pragma unroll
    for (int mi=0;mi<4;++mi)
      #pragma unroll
      for (int ni=0;ni<4;++ni)
        acc[mi][ni] = __builtin_amdgcn_mfma_f32_16x16x32_bf16(af[mi], bfr[ni], acc[mi][ni], 0,0,0);
    __syncthreads();
  }
  // ---- epilogue: bias + residual + LayerNorm ----
  float g4[4], b4[4], bias4[4];
  #pragma unroll
  for (int ni=0;ni<4;++ni){
    int col = w*64 + ni*16 + l15;
    g4[ni] = gamma[col]; b4[ni] = beta[col]; bias4[ni] = biascd[col];
  }
  float psum[4][4] = {}, psq[4][4] = {};
  #pragma unroll
  for (int mi=0;mi<4;++mi)
    #pragma unroll
    for (int ni=0;ni<4;++ni)
      #pragma unroll
      for (int r=0;r<4;++r){
        int row = m0 + mi*16 + lg*4 + r;
        int col = w*64 + ni*16 + l15;
        float v = acc[mi][ni][r] + bias4[ni] + bf2f(xb[(size_t)row*HID + col]);
        acc[mi][ni][r] = v;
        psum[mi][r] += v; psq[mi][r] += v*v;
      }
  #pragma unroll
  for (int mi=0;mi<4;++mi)
    #pragma unroll
    for (int r=0;r<4;++r)
      #pragma unroll
      for (int d=1; d<16; d<<=1){
        psum[mi][r] += __shfl_xor(psum[mi][r], d);
        psq[mi][r]  += __shfl_xor(psq[mi][r], d);
      }
  if (l15 == 0){
    #pragma unroll
    for (int mi=0;mi<4;++mi)
      #pragma unroll
      for (int r=0;r<4;++r){
        int rl = mi*16 + lg*4 + r;
        redbuf[rl][w][0] = psum[mi][r];
        redbuf[rl][w][1] = psq[mi][r];
      }
  }
  __syncthreads();
  if (tid < 64){
    float s=0.f, q=0.f;
    #pragma unroll
    for (int wv=0; wv<8; ++wv){ s += redbuf[tid][wv][0]; q += redbuf[tid][wv][1]; }
    float mu = s*(1.f/512.f);
    float var = q*(1.f/512.f) - mu*mu;
    musig[tid][0] = mu;
    musig[tid][1] = rsqrtf(var + 1e-5f);
  }
  __syncthreads();
  #pragma unroll
  for (int mi=0;mi<4;++mi)
    #pragma unroll
    for (int r=0;r<4;++r){
      int rl = mi*16 + lg*4 + r;
      float mu = musig[rl][0], rs = musig[rl][1];
      #pragma unroll
      for (int ni=0;ni<4;++ni){
        int col = w*64 + ni*16 + l15;
        out[(size_t)(m0+rl)*HID + col] = (acc[mi][ni][r] - mu)*rs*g4[ni] + b4[ni];
      }
    }
}

// =====================================================================
extern "C" void kernel_launch(void* const* d_in, const int* in_sizes, int n_in,
                              void* d_out, int out_size, void* d_ws, size_t ws_size,
                              hipStream_t stream)
{
  const float* x     = (const float*)d_in[0];
  const float* A     = (const float*)d_in[1];
  const float* Wb    = (const float*)d_in[2];
  const float* bb    = (const float*)d_in[3];
  const float* Wc    = (const float*)d_in[4];
  const float* bc    = (const float*)d_in[5];
  const float* Wd    = (const float*)d_in[6];
  const float* bd    = (const float*)d_in[7];
  const float* gamma = (const float*)d_in[8];
  const float* beta  = (const float*)d_in[9];

  char* ws = (char*)d_ws;
  u16*   Ebf    = (u16*)  (ws + OFF_E);
  u16*   Elo    = (u16*)  (ws + OFF_EL);
  float* W32    = (float*)(ws + OFF_W32);
  u16*   wbb    = (u16*)  (ws + OFF_WB);
  u16*   wcdb   = (u16*)  (ws + OFF_WCD);
  float* biascd = (float*)(ws + OFF_BIAS);
  float* Rbuf   = (float*)(ws + OFF_R);
  float* Hc     = (float*)(ws + OFF_HC);
  u16*   Mhi    = (u16*)  (ws + OFF_MH);
  u16*   Mlo    = (u16*)  (ws + OFF_ML);
  u16*   ubuf   = (u16*)  (ws + OFF_U);
  u16*   hsb    = (u16*)  (ws + OFF_HS);
  u16*   xb     = (u16*)  (ws + OFF_XB);

  k_pe<<<2048, 256, 0, stream>>>(x, A, Wb, Wc, Wd, bc, bd, Mhi, Mlo, wbb, wcdb, biascd, xb);
  k_expm<<<16, 256, 0, stream>>>(A, Mhi, Mlo, Ebf, Elo);
  k_bx<<<512, 256, 0, stream>>>(xb, wbb, bb, ubuf);
  k_rec<false><<<80, 256, 0, stream>>>(Ebf, Elo, ubuf, nullptr, Rbuf, nullptr, W32);
  k_scan<<<128, 256, 0, stream>>>(W32, Rbuf, Hc);
  k_rec<true><<<64, 256, 0, stream>>>(Ebf, Elo, ubuf, Hc, nullptr, hsb, W32);
  k_out<<<512, 512, 0, stream>>>(hsb, xb, wcdb, biascd, gamma, beta, (float*)d_out);
}

// Round 5
// 330.010 us; speedup vs baseline: 1.2520x; 1.0546x over previous
//
#include <hip/hip_runtime.h>

#define HID 512
#define ST  256
#define BB  128
#define TT  256
#define BT  (BB*TT)
#define NCH 16
#define CHL 16

typedef unsigned short u16;
typedef unsigned int   u32;
typedef float f32x4  __attribute__((ext_vector_type(4)));
typedef __bf16 bf16x8 __attribute__((ext_vector_type(8)));

// ---- workspace layout (bytes) ----  (end = 0x4400000, proven size)
#define OFF_E    0x0u        // 128 KB  E_hi = expm(A*DT)-I, bf16 [256][256]
#define OFF_EL   0x20000u    // 128 KB  E_lo residual bf16
#define OFF_E16H 0x40000u    // 128 KB  E16_hi = Ad^16 - I, bf16 [s][k]
#define OFF_E16L 0x60000u    // 128 KB  E16_lo
#define OFF_WB   0x80000u    // 256 KB  Wb bf16 [256][512]
#define OFF_WCD  0xC0000u    // 768 KB  Wcd bf16 [512][768]
#define OFF_BIAS 0x180000u   // 2 KB    bc+bd fp32 [512]
#define OFF_MH   0x190000u   // 128 KB  M_hi bf16 (M = 0.1*A)
#define OFF_ML   0x1B0000u   // 128 KB  M_lo bf16
#define OFF_R    0x200000u   // 2 MB    R fp32 [16][128][256] (scan runs in-place)
#define OFF_U    0x400000u   // 16 MB   u bf16 [BT][256]
#define OFF_HS   0x1400000u  // 16 MB   hs bf16 [BT][256]
#define OFF_XB   0x2400000u  // 32 MB   x bf16 [BT][512]

__device__ __forceinline__ u16 f2bf(float f){
  u32 x = __float_as_uint(f);
  return (u16)((x + 0x7FFFu + ((x>>16)&1u)) >> 16);
}
__device__ __forceinline__ float bf2f(u16 u){
  return __uint_as_float(((u32)u)<<16);
}
__device__ __forceinline__ void gld16(const void* g, void* l){
  __builtin_amdgcn_global_load_lds((const __attribute__((address_space(1))) u32*)g,
                                   (__attribute__((address_space(3))) u32*)l, 16, 0, 0);
}

// =====================================================================
// k_pe: pure prep, no LDS, full occupancy.
// =====================================================================
__global__ __launch_bounds__(256) void k_pe(
    const float* __restrict__ x, const float* __restrict__ A,
    const float* __restrict__ Wb, const float* __restrict__ Wc,
    const float* __restrict__ Wd, const float* __restrict__ bc,
    const float* __restrict__ bd, u16* __restrict__ Mhi,
    u16* __restrict__ Mlo, u16* __restrict__ wbb,
    u16* __restrict__ wcdb, float* __restrict__ biascd,
    u16* __restrict__ xb)
{
  long gt = (long)blockIdx.x*256 + threadIdx.x;
  const long np = 2048l*256l;
  for (long i = gt; i < (long)BT*HID/4; i += np){
    float4 v = ((const float4*)x)[i];
    u32 lo = (u32)f2bf(v.x) | ((u32)f2bf(v.y)<<16);
    u32 hi = (u32)f2bf(v.z) | ((u32)f2bf(v.w)<<16);
    uint2 q; q.x = lo; q.y = hi;
    ((uint2*)xb)[i] = q;
  }
  for (long i = gt; i < (long)ST*HID; i += np) wbb[i] = f2bf(Wb[i]);
  for (long i = gt; i < 512l*256l; i += np)
    wcdb[(size_t)(i>>8)*768 + (i&255)] = f2bf(Wc[i]);
  for (long i = gt; i < 512l*512l; i += np)
    wcdb[(size_t)(i>>9)*768 + 256 + (i&511)] = f2bf(Wd[i]);
  for (long i = gt; i < 256l*256l; i += np){
    float m = A[i]*0.1f;
    u16 h = f2bf(m);
    Mhi[i] = h;
    Mlo[i] = f2bf(m - bf2f(h));
  }
  for (long i = gt; i < 512; i += np) biascd[i] = bc[i] + bd[i];
}

// =====================================================================
// k_expm: E = M + M^2/2 + M^3/6, column-partitioned MFMA (16 blocks)
// =====================================================================
__global__ __launch_bounds__(256,1) void k_expm(
    const float* __restrict__ A, const u16* __restrict__ Mhi,
    const u16* __restrict__ Mlo, u16* __restrict__ Ebf,
    u16* __restrict__ Elo)
{
  __shared__ u16 V1h[16*256], V1l[16*256], V2h[16*256];
  int bn = blockIdx.x;
  int tid = threadIdx.x, lane = tid&63, w = tid>>6, l15 = lane&15, lg = lane>>4;
  int j = bn*16 + l15;
  float v1[4][4];
  #pragma unroll
  for (int mi=0;mi<4;++mi)
    #pragma unroll
    for (int r=0;r<4;++r){
      int i = w*64 + mi*16 + lg*4 + r;
      float v = 0.1f * A[(size_t)i*256 + j];
      v1[mi][r] = v;
      u16 h = f2bf(v);
      int off = (l15*512 + i*2) ^ ((l15&7)<<4);
      V1h[off>>1] = h;
      V1l[off>>1] = f2bf(v - bf2f(h));
    }
  __syncthreads();
  f32x4 a2[4] = {};
  #pragma unroll
  for (int kk=0;kk<8;++kk){
    int boff = (l15*512 + (kk*32 + lg*8)*2) ^ ((l15&7)<<4);
    bf16x8 bh = *(const bf16x8*)(V1h + (boff>>1));
    bf16x8 bl = *(const bf16x8*)(V1l + (boff>>1));
    #pragma unroll
    for (int mi=0;mi<4;++mi){
      size_t ro = (size_t)(w*64 + mi*16 + l15)*256 + kk*32 + lg*8;
      bf16x8 ah = *(const bf16x8*)(Mhi + ro);
      bf16x8 al = *(const bf16x8*)(Mlo + ro);
      a2[mi] = __builtin_amdgcn_mfma_f32_16x16x32_bf16(ah, bh, a2[mi],0,0,0);
      a2[mi] = __builtin_amdgcn_mfma_f32_16x16x32_bf16(ah, bl, a2[mi],0,0,0);
      a2[mi] = __builtin_amdgcn_mfma_f32_16x16x32_bf16(al, bh, a2[mi],0,0,0);
    }
  }
  #pragma unroll
  for (int mi=0;mi<4;++mi)
    #pragma unroll
    for (int r=0;r<4;++r){
      int i = w*64 + mi*16 + lg*4 + r;
      int off = (l15*512 + i*2) ^ ((l15&7)<<4);
      V2h[off>>1] = f2bf(a2[mi][r]);
    }
  __syncthreads();
  f32x4 a3[4] = {};
  #pragma unroll
  for (int kk=0;kk<8;++kk){
    int boff = (l15*512 + (kk*32 + lg*8)*2) ^ ((l15&7)<<4);
    bf16x8 bh = *(const bf16x8*)(V2h + (boff>>1));
    #pragma unroll
    for (int mi=0;mi<4;++mi){
      bf16x8 ah = *(const bf16x8*)(Mhi + (size_t)(w*64 + mi*16 + l15)*256 + kk*32 + lg*8);
      a3[mi] = __builtin_amdgcn_mfma_f32_16x16x32_bf16(ah, bh, a3[mi],0,0,0);
    }
  }
  #pragma unroll
  for (int mi=0;mi<4;++mi)
    #pragma unroll
    for (int r=0;r<4;++r){
      int i = w*64 + mi*16 + lg*4 + r;
      float s = v1[mi][r] + 0.5f*a2[mi][r] + (1.f/6.f)*a3[mi][r];
      u16 h = f2bf(s);
      Ebf[(size_t)i*256 + j] = h;
      Elo[(size_t)i*256 + j] = f2bf(s - bf2f(h));
    }
}

// =====================================================================
// k_bx: u = x_bf16 @ Wb^T + bb   (128x128 m97-style, unchanged)
// =====================================================================
__global__ __launch_bounds__(256,1) void k_bx(
    const u16* __restrict__ xb, const u16* __restrict__ wb,
    const float* __restrict__ bb, u16* __restrict__ uout)
{
  __shared__ u16 At[2][128*32];
  __shared__ u16 Bt[2][128*32];
  int bid = blockIdx.x;
  int m0 = (bid>>1)*128, n0 = (bid&1)*128;
  int tid = threadIdx.x, lane = tid&63, w = tid>>6, l15 = lane&15, lg = lane>>4;
  int wrow = (w>>1)*64, wcol = (w&1)*64;
  f32x4 acc[4][4] = {};

  auto stage = [&](int buf, int ki){
    #pragma unroll
    for (int p=0;p<2;++p){
      int c = w + p*4;
      int grow = c*16 + (lane>>2);
      int gk = ki*32 + (lane&3)*8;
      gld16(xb + (size_t)(m0+grow)*HID + gk, &At[buf][c*512]);
      gld16(wb + (size_t)(n0+grow)*HID + gk, &Bt[buf][c*512]);
    }
  };
  stage(0,0);
  __syncthreads();
  for (int ki=0; ki<16; ++ki){
    int buf = ki&1;
    if (ki < 15) stage(buf^1, ki+1);
    bf16x8 af[4], bfr[4];
    #pragma unroll
    for (int mi=0;mi<4;++mi)
      af[mi] = *(const bf16x8*)&At[buf][(wrow + mi*16 + l15)*32 + lg*8];
    #pragma unroll
    for (int ni=0;ni<4;++ni)
      bfr[ni] = *(const bf16x8*)&Bt[buf][(wcol + ni*16 + l15)*32 + lg*8];
    #pragma unroll
    for (int mi=0;mi<4;++mi)
      #pragma unroll
      for (int ni=0;ni<4;++ni)
        acc[mi][ni] = __builtin_amdgcn_mfma_f32_16x16x32_bf16(af[mi], bfr[ni], acc[mi][ni], 0,0,0);
    __syncthreads();
  }
  float bb4[4];
  #pragma unroll
  for (int ni=0;ni<4;++ni) bb4[ni] = bb[n0 + wcol + ni*16 + l15];
  #pragma unroll
  for (int mi=0;mi<4;++mi)
    #pragma unroll
    for (int ni=0;ni<4;++ni)
      #pragma unroll
      for (int r=0;r<4;++r){
        int row = m0 + wrow + mi*16 + lg*4 + r;
        int col = n0 + wcol + ni*16 + l15;
        uout[(size_t)row*ST + col] = f2bf(acc[mi][ni][r] + bb4[ni]);
      }
}

// =====================================================================
// k_rec: chunked recurrence, CHL=16.
//   WRITE_HS=false: blocks [0,128): local pass -> R[j]
//                   blocks [128,144): identity -> E16 = Ad^16 - I (hi/lo)
//   WRITE_HS=true : fixup from Rbuf[j-1] (=S_j), writes hs
// =====================================================================
template<bool WRITE_HS>
__global__ __launch_bounds__(256,1) void k_rec(
    const u16* __restrict__ Ebf, const u16* __restrict__ Elo,
    const u16* __restrict__ ubuf, float* __restrict__ Rbuf,
    u16* __restrict__ hsb, u16* __restrict__ E16h,
    u16* __restrict__ E16l)
{
  int tid = threadIdx.x, lane = tid&63, w = tid>>6, l15 = lane&15, lg = lane>>4;
  __shared__ u16 hlds[2][16*256];

  if (!WRITE_HS && blockIdx.x >= 128){
    // ---- identity batch: rows of (Ad^16)^T -> E16 hi/lo, [s][k] layout ----
    int b0 = ((int)blockIdx.x - 128)*16;
    bf16x8 ef[4][8], ef2[4][8];
    #pragma unroll
    for (int nt=0; nt<4; ++nt){
      int srow = w*64 + nt*16 + l15;
      #pragma unroll
      for (int kk=0; kk<8; ++kk){
        ef [nt][kk] = *(const bf16x8*)(Ebf + (size_t)srow*256 + kk*32 + lg*8);
        ef2[nt][kk] = *(const bf16x8*)(Elo + (size_t)srow*256 + kk*32 + lg*8);
      }
    }
    f32x4 acc[4];
    #pragma unroll
    for (int nt=0;nt<4;++nt)
      #pragma unroll
      for (int r=0;r<4;++r)
        acc[nt][r] = (b0 + lg*4 + r == w*64 + nt*16 + l15) ? 1.f : 0.f;
    for (int it=0; it<CHL; ++it){
      u16* hb = hlds[it&1];
      #pragma unroll
      for (int nt=0;nt<4;++nt)
        #pragma unroll
        for (int r=0;r<4;++r){
          int row = lg*4 + r;
          int sc  = w*64 + nt*16 + l15;
          int off = (row*512 + sc*2) ^ ((row&7)<<4);
          hb[off>>1] = f2bf(acc[nt][r]);
        }
      __syncthreads();
      bf16x8 af[8];
      #pragma unroll
      for (int kk=0;kk<8;++kk){
        int off = (l15*512 + (kk*32 + lg*8)*2) ^ ((l15&7)<<4);
        af[kk] = *(const bf16x8*)(hlds[it&1] + (off>>1));
      }
      #pragma unroll
      for (int nt=0;nt<4;++nt)
        #pragma unroll
        for (int kk=0;kk<8;++kk)
          acc[nt] = __builtin_amdgcn_mfma_f32_16x16x32_bf16(af[kk], ef[nt][kk], acc[nt], 0,0,0);
      #pragma unroll
      for (int nt=0;nt<4;++nt)
        #pragma unroll
        for (int kk=0;kk<8;++kk)
          acc[nt] = __builtin_amdgcn_mfma_f32_16x16x32_bf16(af[kk], ef2[nt][kk], acc[nt], 0,0,0);
    }
    // acc(krow, col) = Ad16[col][krow]; store E16[s=col][k=krow] = val - I
    #pragma unroll
    for (int nt=0;nt<4;++nt)
      #pragma unroll
      for (int r=0;r<4;++r){
        int krow = b0 + lg*4 + r;
        int col  = w*64 + nt*16 + l15;
        float v = acc[nt][r] - ((krow == col) ? 1.f : 0.f);
        u16 h = f2bf(v);
        E16h[(size_t)col*256 + krow] = h;
        E16l[(size_t)col*256 + krow] = f2bf(v - bf2f(h));
      }
    return;
  }

  // ---- main recurrence path ----
  int j = (int)blockIdx.x >> 3;
  int b0 = ((int)blockIdx.x & 7)*16;

  bf16x8 ef[4][8];
  #pragma unroll
  for (int nt=0; nt<4; ++nt){
    int srow = w*64 + nt*16 + l15;
    #pragma unroll
    for (int kk=0; kk<8; ++kk)
      ef[nt][kk] = *(const bf16x8*)(Ebf + (size_t)srow*256 + kk*32 + lg*8);
  }

  f32x4 acc[4];
  #pragma unroll
  for (int nt=0;nt<4;++nt){
    if (WRITE_HS && j > 0){
      #pragma unroll
      for (int r=0;r<4;++r)
        acc[nt][r] = Rbuf[((size_t)(j-1)*BB + b0 + lg*4 + r)*ST + w*64 + nt*16 + l15];
    } else {
      acc[nt] = (f32x4){0.f,0.f,0.f,0.f};
    }
  }

  int t0 = j*CHL;
  float uv[4][4];
  #pragma unroll
  for (int nt=0;nt<4;++nt)
    #pragma unroll
    for (int r=0;r<4;++r)
      uv[nt][r] = bf2f(ubuf[((size_t)(b0 + lg*4 + r)*TT + t0)*ST + w*64 + nt*16 + l15]);

  for (int it=0; it<CHL; ++it){
    int t = t0 + it;
    u16* hb = hlds[it&1];
    #pragma unroll
    for (int nt=0;nt<4;++nt)
      #pragma unroll
      for (int r=0;r<4;++r){
        int row = lg*4 + r;
        int sc  = w*64 + nt*16 + l15;
        int off = (row*512 + sc*2) ^ ((row&7)<<4);
        hb[off>>1] = f2bf(acc[nt][r]);
      }
    __syncthreads();
    float uvn[4][4];
    if (it+1 < CHL){
      #pragma unroll
      for (int nt=0;nt<4;++nt)
        #pragma unroll
        for (int r=0;r<4;++r)
          uvn[nt][r] = bf2f(ubuf[((size_t)(b0 + lg*4 + r)*TT + t + 1)*ST + w*64 + nt*16 + l15]);
    }
    bf16x8 af[8];
    #pragma unroll
    for (int kk=0;kk<8;++kk){
      int off = (l15*512 + (kk*32 + lg*8)*2) ^ ((l15&7)<<4);
      af[kk] = *(const bf16x8*)(hb + (off>>1));
    }
    #pragma unroll
    for (int nt=0;nt<4;++nt)
      #pragma unroll
      for (int kk=0;kk<8;++kk)
        acc[nt] = __builtin_amdgcn_mfma_f32_16x16x32_bf16(af[kk], ef[nt][kk], acc[nt], 0,0,0);
    #pragma unroll
    for (int nt=0;nt<4;++nt)
      #pragma unroll
      for (int r=0;r<4;++r)
        acc[nt][r] += uv[nt][r];
    if (WRITE_HS){
      #pragma unroll
      for (int nt=0;nt<4;++nt)
        #pragma unroll
        for (int r=0;r<4;++r)
          hsb[((size_t)(b0 + lg*4 + r)*TT + t)*ST + w*64 + nt*16 + l15] = f2bf(acc[nt][r]);
    }
    if (it+1 < CHL){
      #pragma unroll
      for (int nt=0;nt<4;++nt)
        #pragma unroll
        for (int r=0;r<4;++r)
          uv[nt][r] = uvn[nt][r];
    }
  }
  if (!WRITE_HS){
    #pragma unroll
    for (int nt=0;nt<4;++nt)
      #pragma unroll
      for (int r=0;r<4;++r)
        Rbuf[((size_t)j*BB + b0 + lg*4 + r)*ST + w*64 + nt*16 + l15] = acc[nt][r];
  }
}

// =====================================================================
// k_scan: MFMA chunk-carry scan, in-place in Rbuf.
//   S_1 = R_0 (slot 0 as-is); for j=2..15:
//   S_j = S_{j-1} + S_{j-1}@E16^T (hi/lo) + R_{j-1};  S_j -> slot j-1
// 8 blocks x 16 batch rows.
// =====================================================================
__global__ __launch_bounds__(256,1) void k_scan(
    const u16* __restrict__ E16h, const u16* __restrict__ E16l,
    float* __restrict__ Rbuf)
{
  int b0 = blockIdx.x*16;
  int tid = threadIdx.x, lane = tid&63, w = tid>>6, l15 = lane&15, lg = lane>>4;
  __shared__ u16 hh[2][16*256], hl[2][16*256];
  bf16x8 efh[4][8], efl[4][8];
  #pragma unroll
  for (int nt=0; nt<4; ++nt){
    int srow = w*64 + nt*16 + l15;
    #pragma unroll
    for (int kk=0; kk<8; ++kk){
      efh[nt][kk] = *(const bf16x8*)(E16h + (size_t)srow*256 + kk*32 + lg*8);
      efl[nt][kk] = *(const bf16x8*)(E16l + (size_t)srow*256 + kk*32 + lg*8);
    }
  }
  int col[4], rowg[4];
  #pragma unroll
  for (int nt=0;nt<4;++nt) col[nt] = w*64 + nt*16 + l15;
  #pragma unroll
  for (int r=0;r<4;++r) rowg[r] = b0 + lg*4 + r;

  f32x4 acc[4];
  #pragma unroll
  for (int nt=0;nt<4;++nt)
    #pragma unroll
    for (int r=0;r<4;++r)
      acc[nt][r] = Rbuf[(size_t)rowg[r]*ST + col[nt]];   // S_1 = R_0

  for (int j=2; j<NCH; ++j){
    // prefetch R_{j-1}
    float rv[4][4];
    #pragma unroll
    for (int nt=0;nt<4;++nt)
      #pragma unroll
      for (int r=0;r<4;++r)
        rv[nt][r] = Rbuf[((size_t)(j-1)*BB + rowg[r])*ST + col[nt]];
    // stage S_{j-1} hi/lo
    u16* bh = hh[j&1]; u16* bl = hl[j&1];
    #pragma unroll
    for (int nt=0;nt<4;++nt)
      #pragma unroll
      for (int r=0;r<4;++r){
        int row = lg*4 + r;
        int off = (row*512 + col[nt]*2) ^ ((row&7)<<4);
        float v = acc[nt][r];
        u16 h = f2bf(v);
        bh[off>>1] = h;
        bl[off>>1] = f2bf(v - bf2f(h));
      }
    __syncthreads();
    bf16x8 ah[8], al[8];
    #pragma unroll
    for (int kk=0;kk<8;++kk){
      int off = (l15*512 + (kk*32 + lg*8)*2) ^ ((l15&7)<<4);
      ah[kk] = *(const bf16x8*)(bh + (off>>1));
      al[kk] = *(const bf16x8*)(bl + (off>>1));
    }
    #pragma unroll
    for (int nt=0;nt<4;++nt)
      #pragma unroll
      for (int kk=0;kk<8;++kk){
        acc[nt] = __builtin_amdgcn_mfma_f32_16x16x32_bf16(ah[kk], efh[nt][kk], acc[nt], 0,0,0);
        acc[nt] = __builtin_amdgcn_mfma_f32_16x16x32_bf16(al[kk], efh[nt][kk], acc[nt], 0,0,0);
        acc[nt] = __builtin_amdgcn_mfma_f32_16x16x32_bf16(ah[kk], efl[nt][kk], acc[nt], 0,0,0);
      }
    #pragma unroll
    for (int nt=0;nt<4;++nt)
      #pragma unroll
      for (int r=0;r<4;++r){
        acc[nt][r] += rv[nt][r];
        Rbuf[((size_t)(j-1)*BB + rowg[r])*ST + col[nt]] = acc[nt][r];  // S_j -> slot j-1
      }
  }
}

// =====================================================================
// k_out: out = LN( hs@Wc^T + x@Wd^T + bias + x )
// BM=128, BN=512, 1024 threads (16 waves, 2M x 8N), K=768
// =====================================================================
__global__ __launch_bounds__(1024,4) void k_out(
    const u16* __restrict__ hsb, const u16* __restrict__ xb,
    const u16* __restrict__ wcd, const float* __restrict__ biascd,
    const float* __restrict__ gamma, const float* __restrict__ beta,
    float* __restrict__ out)
{
  __shared__ u16 At[2][128*32];
  __shared__ u16 Bt[2][512*32];
  __shared__ float redbuf[128][8][2];
  __shared__ float musig[128][2];
  int m0 = blockIdx.x*128;
  int tid = threadIdx.x, lane = tid&63, wid = tid>>6, l15 = lane&15, lg = lane>>4;
  int wr = wid>>3, wc = wid&7;
  f32x4 acc[4][4] = {};

  auto stage = [&](int buf, int ki){
    #pragma unroll
    for (int p=0;p<2;++p){
      int c = wid*2 + p;   // 32 chunks x 16 rows = 512 B-rows
      gld16(wcd + (size_t)(c*16 + (lane>>2))*768 + ki*32 + (lane&3)*8, &Bt[buf][c*512]);
    }
    if (wid < 8){
      int grow = m0 + wid*16 + (lane>>2);
      const u16* g;
      if (ki < 8) g = hsb + (size_t)grow*ST  + ki*32 + (lane&3)*8;
      else        g = xb  + (size_t)grow*HID + (ki-8)*32 + (lane&3)*8;
      gld16(g, &At[buf][wid*512]);
    }
  };
  stage(0,0);
  __syncthreads();
  for (int ki=0; ki<24; ++ki){
    int buf = ki&1;
    if (ki < 23) stage(buf^1, ki+1);
    bf16x8 af[4], bfr[4];
    #pragma unroll
    for (int mi=0;mi<4;++mi)
      af[mi] = *(const bf16x8*)&At[buf][(wr*64 + mi*16 + l15)*32 + lg*8];
    #pragma unroll
    for (int ni=0;ni<4;++ni)
      bfr[ni] = *(const bf16x8*)&Bt[buf][(wc*64 + ni*16 + l15)*32 + lg*8];
    #pragma unroll
    for (int mi=0;mi<4;++mi)
      #pragma unroll
      for (int ni=0;ni<4;++ni)
        acc[mi][ni] = __builtin_amdgcn_mfma_f32_16x16x32_bf16(af[mi], bfr[ni], acc[mi][ni], 0,0,0);
    __syncthreads();
  }
  // ---- epilogue: bias + residual + LayerNorm ----
  float g4[4], b4[4], bias4[4];
  #pragma unroll
  for (int ni=0;ni<4;++ni){
    int c = wc*64 + ni*16 + l15;
    g4[ni] = gamma[c]; b4[ni] = beta[c]; bias4[ni] = biascd[c];
  }
  float psum[4][4] = {}, psq[4][4] = {};
  #pragma unroll
  for (int mi=0;mi<4;++mi)
    #pragma unroll
    for (int ni=0;ni<4;++ni)
      #pragma unroll
      for (int r=0;r<4;++r){
        int row = m0 + wr*64 + mi*16 + lg*4 + r;
        int c   = wc*64 + ni*16 + l15;
        float v = acc[mi][ni][r] + bias4[ni] + bf2f(xb[(size_t)row*HID + c]);
        acc[mi][ni][r] = v;
        psum[mi][r] += v; psq[mi][r] += v*v;
      }
  #pragma unroll
  for (int mi=0;mi<4;++mi)
    #pragma unroll
    for (int r=0;r<4;++r)
      #pragma unroll
      for (int d=1; d<16; d<<=1){
        psum[mi][r] += __shfl_xor(psum[mi][r], d);
        psq[mi][r]  += __shfl_xor(psq[mi][r], d);
      }
  if (l15 == 0){
    #pragma unroll
    for (int mi=0;mi<4;++mi)
      #pragma unroll
      for (int r=0;r<4;++r){
        int rl = wr*64 + mi*16 + lg*4 + r;
        redbuf[rl][wc][0] = psum[mi][r];
        redbuf[rl][wc][1] = psq[mi][r];
      }
  }
  __syncthreads();
  if (tid < 128){
    float s=0.f, q=0.f;
    #pragma unroll
    for (int wv=0; wv<8; ++wv){ s += redbuf[tid][wv][0]; q += redbuf[tid][wv][1]; }
    float mu = s*(1.f/512.f);
    float var = q*(1.f/512.f) - mu*mu;
    musig[tid][0] = mu;
    musig[tid][1] = rsqrtf(var + 1e-5f);
  }
  __syncthreads();
  #pragma unroll
  for (int mi=0;mi<4;++mi)
    #pragma unroll
    for (int r=0;r<4;++r){
      int rl = wr*64 + mi*16 + lg*4 + r;
      float mu = musig[rl][0], rs = musig[rl][1];
      #pragma unroll
      for (int ni=0;ni<4;++ni){
        int c = wc*64 + ni*16 + l15;
        out[(size_t)(m0+rl)*HID + c] = (acc[mi][ni][r] - mu)*rs*g4[ni] + b4[ni];
      }
    }
}

// =====================================================================
extern "C" void kernel_launch(void* const* d_in, const int* in_sizes, int n_in,
                              void* d_out, int out_size, void* d_ws, size_t ws_size,
                              hipStream_t stream)
{
  const float* x     = (const float*)d_in[0];
  const float* A     = (const float*)d_in[1];
  const float* Wb    = (const float*)d_in[2];
  const float* bb    = (const float*)d_in[3];
  const float* Wc    = (const float*)d_in[4];
  const float* bc    = (const float*)d_in[5];
  const float* Wd    = (const float*)d_in[6];
  const float* bd    = (const float*)d_in[7];
  const float* gamma = (const float*)d_in[8];
  const float* beta  = (const float*)d_in[9];

  char* ws = (char*)d_ws;
  u16*   Ebf    = (u16*)  (ws + OFF_E);
  u16*   Elo    = (u16*)  (ws + OFF_EL);
  u16*   E16h   = (u16*)  (ws + OFF_E16H);
  u16*   E16l   = (u16*)  (ws + OFF_E16L);
  u16*   wbb    = (u16*)  (ws + OFF_WB);
  u16*   wcdb   = (u16*)  (ws + OFF_WCD);
  float* biascd = (float*)(ws + OFF_BIAS);
  u16*   Mhi    = (u16*)  (ws + OFF_MH);
  u16*   Mlo    = (u16*)  (ws + OFF_ML);
  float* Rbuf   = (float*)(ws + OFF_R);
  u16*   ubuf   = (u16*)  (ws + OFF_U);
  u16*   hsb    = (u16*)  (ws + OFF_HS);
  u16*   xb     = (u16*)  (ws + OFF_XB);

  k_pe<<<2048, 256, 0, stream>>>(x, A, Wb, Wc, Wd, bc, bd, Mhi, Mlo, wbb, wcdb, biascd, xb);
  k_expm<<<16, 256, 0, stream>>>(A, Mhi, Mlo, Ebf, Elo);
  k_bx<<<512, 256, 0, stream>>>(xb, wbb, bb, ubuf);
  k_rec<false><<<144, 256, 0, stream>>>(Ebf, Elo, ubuf, Rbuf, nullptr, E16h, E16l);
  k_scan<<<8, 256, 0, stream>>>(E16h, E16l, Rbuf);
  k_rec<true><<<128, 256, 0, stream>>>(Ebf, Elo, ubuf, Rbuf, hsb, nullptr, nullptr);
  k_out<<<256, 1024, 0, stream>>>(hsb, xb, wcdb, biascd, gamma, beta, (float*)d_out);
}